// Round 6
// baseline (126.702 us; speedup 1.0000x reference)
//
#include <hip/hip_runtime.h>

// LinearAttention collapsed:
//   dots[m,h] = sum_{d in head h} (X@Wk^T)*(X@Wv^T)   [dual GEMM, BN=64=1 head, 2 blocks/CU]
//   qsum = X @ Wqs^T ; dotb = X @ CB^T                 [side GEMM, 64 trailing blocks]
//   cum = cumsum_s((dots + dotb + dbc)*mask^2); coef = cum*(qsum+bqs)
//   out = coef @ WosT + bo ; state[b,h,:,:] = cum[b, S-1, h]

typedef __attribute__((ext_vector_type(4))) float f32x4;
typedef __attribute__((ext_vector_type(8))) short bf16x8;
typedef __attribute__((ext_vector_type(8))) unsigned short u16x8;
typedef unsigned int u32;

#define GLDS16(g, l)                                                            \
  __builtin_amdgcn_global_load_lds((const __attribute__((address_space(1))) u32*)(g), \
                                   (__attribute__((address_space(3))) u32*)(l), 16, 0, 0)
#define MFMA16(a, b, c) __builtin_amdgcn_mfma_f32_16x16x32_bf16(a, b, c, 0, 0, 0)

__device__ __forceinline__ unsigned short f2bf(float f) {
  union { float f; u32 u; } x; x.f = f;
  u32 r = (x.u + 0x7fffu + ((x.u >> 16) & 1u)) >> 16;
  return (unsigned short)r;
}

// ---------------- fused prep: Wk/Wv->bf16, weight sums, X->bf16 ----------------
__global__ void k_prep(const float* __restrict__ X, unsigned short* __restrict__ Xb,
                       const float* __restrict__ Wq, const float* __restrict__ bq,
                       const float* __restrict__ Wk, const float* __restrict__ bk,
                       const float* __restrict__ Wv, const float* __restrict__ bv,
                       const float* __restrict__ Wo,
                       unsigned short* __restrict__ Wkb, unsigned short* __restrict__ Wvb,
                       unsigned short* __restrict__ SWb, float* __restrict__ WosT,
                       float* __restrict__ scal) {
  int blk = blockIdx.x, t = threadIdx.x;
  if (blk < 2048) {                    // Wk/Wv convert
    const float* src = (blk < 1024) ? Wk : Wv;
    unsigned short* dst = (blk < 1024) ? Wkb : Wvb;
    size_t i = ((size_t)(blk & 1023) * 256 + t) * 4;
    f32x4 v = *(const f32x4*)(src + i);
    dst[i + 0] = f2bf(v.x); dst[i + 1] = f2bf(v.y);
    dst[i + 2] = f2bf(v.z); dst[i + 3] = f2bf(v.w);
  } else if (blk < 2241) {             // weight sums
    int b2 = blk - 2048;
    if (b2 < 128) {
      int o = b2 * 256 + t;
      int r = o >> 10, c = o & 1023;
      float s = 0.f;
      if (r < 16) {
        for (int d = 0; d < 64; ++d) s += Wq[(size_t)(r * 64 + d) * 1024 + c];
      } else {
        int h = r - 16;
        for (int d = 0; d < 64; ++d) {
          int j = h * 64 + d;
          s += bv[j] * Wk[(size_t)j * 1024 + c] + bk[j] * Wv[(size_t)j * 1024 + c];
        }
      }
      SWb[o] = f2bf(s);
    } else if (b2 < 192) {
      int o = (b2 - 128) * 256 + t;
      int h = o >> 10, j = o & 1023;
      float s = 0.f;
      for (int d = 0; d < 64; ++d) s += Wo[(size_t)j * 1024 + h * 64 + d];
      WosT[o] = s;
    } else {
      if (t < 16) {
        float s = 0.f;
        for (int d = 0; d < 64; ++d) s += bq[t * 64 + d];
        scal[t] = s;
      } else if (t < 32) {
        int h = t - 16;
        float s = 0.f;
        for (int d = 0; d < 64; ++d) s += bk[h * 64 + d] * bv[h * 64 + d];
        scal[t] = s;
      }
    }
  } else {                             // X convert
    size_t i = ((size_t)(blk - 2241) * 256 + t) * 8;
    f32x4 a = *(const f32x4*)(X + i);
    f32x4 b = *(const f32x4*)(X + i + 4);
    u16x8 o;
    o[0] = f2bf(a.x); o[1] = f2bf(a.y); o[2] = f2bf(a.z); o[3] = f2bf(a.w);
    o[4] = f2bf(b.x); o[5] = f2bf(b.y); o[6] = f2bf(b.z); o[7] = f2bf(b.w);
    *(u16x8*)(Xb + i) = o;
  }
}

// ---------------- dual GEMM: BM=256, BN=64 (one head), BK=32, 8 waves (4M x 2N) ----------
// 2 blocks/CU (launch_bounds 512,4). 2 LDS bufs, depth-1 prefetch, one vmcnt(0)+barrier/tile.
// Compiler schedules lgkmcnt (no explicit drain). Buf (elems): A@0 (8192), Bk@8192 (2048),
// Bv@10240 (2048) [side: SW@8192 (1024)]. Buf stride 12288; 2 bufs = 49152 B dynamic LDS.
// Row = 32 bf16 = 4 x 16B units; swizzle: unit ^= (row & 3) on source and read.
#define NT 32
#define BUFS 12288
__global__ __launch_bounds__(512, 4) void k_dualgemm(
    const unsigned short* __restrict__ Xb,
    const unsigned short* __restrict__ Wkb,
    const unsigned short* __restrict__ Wvb,
    const unsigned short* __restrict__ SWb,
    float* __restrict__ dots2, float* __restrict__ qsumT, float* __restrict__ dotbT) {
  extern __shared__ __align__(16) unsigned short lds[];
  int orig = blockIdx.x;
  int tid = threadIdx.x, wid = tid >> 6, lane = tid & 63;
  int fr = lane & 15, fg = lane >> 4;
  int u_r = (fg ^ (fr & 3)) << 3;          // swizzled 16B-unit offset within a row (elems)

  if (orig >= 1024) {  // ================= side path: X @ SWb^T (N=32) =================
    int rowblk = orig - 1024;
    int row0 = rowblk << 8;
    // staging sources
    int U0 = tid, r0 = U0 >> 2;
    int U1 = tid + 512, r1 = U1 >> 2;
    const unsigned short* sA0 = Xb + (size_t)(row0 + r0) * 1024 + (((U0 & 3) ^ (r0 & 3)) << 3);
    const unsigned short* sA1 = Xb + (size_t)(row0 + r1) * 1024 + (((U1 & 3) ^ (r1 & 3)) << 3);
    int Us0 = lane, rs0 = Us0 >> 2;
    int Us1 = 64 + lane, rs1 = Us1 >> 2;
    const unsigned short* sS0 = SWb + (size_t)rs0 * 1024 + (((Us0 & 3) ^ (rs0 & 3)) << 3);
    const unsigned short* sS1 = SWb + (size_t)rs1 * 1024 + (((Us1 & 3) ^ (rs1 & 3)) << 3);
    int dA0 = wid << 9, dA1 = 4096 + (wid << 9);
    f32x4 acc[2][2] = {{0}};
    int aoff0 = (wid * 32 + fr) * 32 + u_r;
    int aoff1 = (wid * 32 + 16 + fr) * 32 + u_r;
    int soff0 = 8192 + fr * 32 + u_r;
    int soff1 = 8192 + (16 + fr) * 32 + u_r;
    // prologue
    GLDS16(sA0, lds + dA0);
    GLDS16(sA1, lds + dA1);
    if (wid == 0) { GLDS16(sS0, lds + 8192); GLDS16(sS1, lds + 8192 + 512); }
    asm volatile("s_waitcnt vmcnt(0)" ::: "memory");
    __builtin_amdgcn_s_barrier();
    for (int t = 0; t < NT; ++t) {
      int rb = (t & 1) * BUFS, wb = ((t + 1) & 1) * BUFS, ko = (t + 1) << 5;
      if (t + 1 < NT) {
        GLDS16(sA0 + ko, lds + wb + dA0);
        GLDS16(sA1 + ko, lds + wb + dA1);
        if (wid == 0) { GLDS16(sS0 + ko, lds + wb + 8192); GLDS16(sS1 + ko, lds + wb + 8192 + 512); }
      }
      bf16x8 a0 = *(const bf16x8*)(lds + rb + aoff0);
      bf16x8 a1 = *(const bf16x8*)(lds + rb + aoff1);
      bf16x8 s0 = *(const bf16x8*)(lds + rb + soff0);
      bf16x8 s1 = *(const bf16x8*)(lds + rb + soff1);
      acc[0][0] = MFMA16(a0, s0, acc[0][0]);
      acc[0][1] = MFMA16(a0, s1, acc[0][1]);
      acc[1][0] = MFMA16(a1, s0, acc[1][0]);
      acc[1][1] = MFMA16(a1, s1, acc[1][1]);
      asm volatile("s_waitcnt vmcnt(0)" ::: "memory");
      __builtin_amdgcn_s_barrier();
    }
    size_t mbase = row0 + wid * 32;
#pragma unroll
    for (int mi = 0; mi < 2; ++mi)
#pragma unroll
      for (int ni = 0; ni < 2; ++ni) {
        float* dst = (ni == 0) ? qsumT : dotbT;
#pragma unroll
        for (int q = 0; q < 4; ++q)
          dst[(size_t)fr * 16384 + mbase + mi * 16 + fg * 4 + q] = acc[mi][ni][q];
      }
    return;
  }

  // ================= dual path =================
  int wg = (orig & 7) * 128 + (orig >> 3);   // XCD-chunked swizzle (1024 % 8 == 0)
  int bx = wg & 15, by = wg >> 4;            // bx = head, by = row block
  int row0 = by << 8, col0 = bx << 6;
  int wrM = wid >> 1, wcN = wid & 1;

  // staging sources (pre-swizzled 16B units)
  int U0 = tid, r0 = U0 >> 2;
  int U1 = tid + 512, r1 = U1 >> 2;
  const unsigned short* sA0 = Xb + (size_t)(row0 + r0) * 1024 + (((U0 & 3) ^ (r0 & 3)) << 3);
  const unsigned short* sA1 = Xb + (size_t)(row0 + r1) * 1024 + (((U1 & 3) ^ (r1 & 3)) << 3);
  int Ub = tid & 255, rB = Ub >> 2;
  int uswB = ((Ub & 3) ^ (rB & 3)) << 3;
  const unsigned short* sB = (wid < 4) ? (Wkb + (size_t)(col0 + rB) * 1024 + uswB)
                                       : (Wvb + (size_t)(col0 + rB) * 1024 + uswB);
  int dA0 = wid << 9, dA1 = 4096 + (wid << 9);
  int dB = ((wid < 4) ? 8192 : 10240) + ((wid & 3) << 9);

  // fragment read offsets (elems within buffer)
  int aoff[4], bkoff[2], bvoff[2];
#pragma unroll
  for (int mi = 0; mi < 4; ++mi) aoff[mi] = (wrM * 64 + mi * 16 + fr) * 32 + u_r;
#pragma unroll
  for (int ni = 0; ni < 2; ++ni) {
    bkoff[ni] = 8192 + (wcN * 32 + ni * 16 + fr) * 32 + u_r;
    bvoff[ni] = 10240 + (wcN * 32 + ni * 16 + fr) * 32 + u_r;
  }

  f32x4 ck[4][2] = {{0}}, cv[4][2] = {{0}};

  // prologue: stage tile 0 -> buf0
  GLDS16(sA0, lds + dA0);
  GLDS16(sA1, lds + dA1);
  GLDS16(sB, lds + dB);
  asm volatile("s_waitcnt vmcnt(0)" ::: "memory");
  __builtin_amdgcn_s_barrier();

  for (int t = 0; t < NT; ++t) {
    int rb = (t & 1) * BUFS, wb = ((t + 1) & 1) * BUFS, ko = (t + 1) << 5;
    if (t + 1 < NT) {
      GLDS16(sA0 + ko, lds + wb + dA0);
      GLDS16(sA1 + ko, lds + wb + dA1);
      GLDS16(sB + ko, lds + wb + dB);
    }
    bf16x8 a[4], bk[2], bv[2];
#pragma unroll
    for (int mi = 0; mi < 4; ++mi) a[mi] = *(const bf16x8*)(lds + rb + aoff[mi]);
#pragma unroll
    for (int ni = 0; ni < 2; ++ni) {
      bk[ni] = *(const bf16x8*)(lds + rb + bkoff[ni]);
      bv[ni] = *(const bf16x8*)(lds + rb + bvoff[ni]);
    }
    __builtin_amdgcn_s_setprio(1);
#pragma unroll
    for (int mi = 0; mi < 4; ++mi)
#pragma unroll
      for (int ni = 0; ni < 2; ++ni) {
        ck[mi][ni] = MFMA16(a[mi], bk[ni], ck[mi][ni]);
        cv[mi][ni] = MFMA16(a[mi], bv[ni], cv[mi][ni]);
      }
    __builtin_amdgcn_s_setprio(0);
    asm volatile("s_waitcnt vmcnt(0)" ::: "memory");
    __builtin_amdgcn_s_barrier();
  }

  // epilogue: per-wave partial dots over its 32 cols
  float part[4][4];
#pragma unroll
  for (int mi = 0; mi < 4; ++mi)
#pragma unroll
    for (int q = 0; q < 4; ++q) {
      float s = 0.f;
#pragma unroll
      for (int ni = 0; ni < 2; ++ni) s += ck[mi][ni][q] * cv[mi][ni][q];
      part[mi][q] = s;
    }
#pragma unroll
  for (int r = 0; r < 4; ++r) {
#pragma unroll
    for (int mi = 0; mi < 4; ++mi)
#pragma unroll
      for (int q = 0; q < 4; ++q)
        part[mi][q] += __shfl_xor(part[mi][q], 1 << r, 64);
  }
  if (fr == 0) {
#pragma unroll
    for (int mi = 0; mi < 4; ++mi)
#pragma unroll
      for (int q = 0; q < 4; ++q)
        dots2[(size_t)(bx * 2 + wcN) * 16384 + row0 + wrM * 64 + mi * 16 + fg * 4 + q] =
            part[mi][q];
  }
}

// ---------------- cumsum + coef + state ----------------
__global__ void k_cumsum(const float* __restrict__ dots2, const float* __restrict__ dotbT,
                         const float* __restrict__ qsumT, const float* __restrict__ scal,
                         const float* __restrict__ mask,
                         float* __restrict__ coef, float* __restrict__ state) {
  __shared__ float csum[256];
  int b = blockIdx.x >> 4, h = blockIdx.x & 15;
  int t = threadIdx.x;
  float bqs = scal[h], dbc = scal[16 + h];
  size_t m0 = (size_t)b * 4096;
  const float* d0 = dots2 + (size_t)(h * 2) * 16384 + m0;
  const float* d1 = dots2 + (size_t)(h * 2 + 1) * 16384 + m0;
  const float* dbo = dotbT + (size_t)h * 16384 + m0;
  const float* qso = qsumT + (size_t)h * 16384 + m0;
  const float* mko = mask + m0;
  float loc[16], run = 0.f;
  int s0 = t * 16;
#pragma unroll
  for (int i = 0; i < 16; ++i) {
    int ii = s0 + i;
    float mk = mko[ii];
    float d = (d0[ii] + d1[ii] + dbo[ii] + dbc) * mk * mk;
    run += d;
    loc[i] = run;
  }
  csum[t] = run;
  __syncthreads();
  for (int off = 1; off < 256; off <<= 1) {
    float v = (t >= off) ? csum[t - off] : 0.f;
    __syncthreads();
    csum[t] += v;
    __syncthreads();
  }
  float prefix = csum[t] - run;
#pragma unroll
  for (int i = 0; i < 16; ++i) {
    int ii = s0 + i;
    float cum = prefix + loc[i];
    coef[(m0 + ii) * 16 + h] = cum * (qso[ii] + bqs);
  }
  float total = csum[255];
  float* sp = state + (size_t)(b * 16 + h) * 4096;
  for (int i = t; i < 4096; i += 256) sp[i] = total;
}

// ---------------- output GEMM: out = coef(16384x16) @ WosT(16x1024) + bo ----------------
__global__ __launch_bounds__(256) void k_outgemm(const float* __restrict__ coef,
                                                 const float* __restrict__ WosT,
                                                 const float* __restrict__ bo,
                                                 float* __restrict__ out) {
  int t = threadIdx.x;
  int j0 = t * 4;
  f32x4 w4[16];
#pragma unroll
  for (int hh = 0; hh < 16; ++hh) w4[hh] = *(const f32x4*)&WosT[hh * 1024 + j0];
  f32x4 bov = *(const f32x4*)&bo[j0];
  size_t m0 = (size_t)blockIdx.x * 32;
  for (int mi = 0; mi < 32; ++mi) {
    size_t m = m0 + mi;
    const float* cm = &coef[m * 16];
    f32x4 acc = bov;
#pragma unroll
    for (int hh = 0; hh < 16; ++hh) acc += w4[hh] * cm[hh];
    *(f32x4*)&out[m * 1024 + j0] = acc;
  }
}

extern "C" void kernel_launch(void* const* d_in, const int* in_sizes, int n_in,
                              void* d_out, int out_size, void* d_ws, size_t ws_size,
                              hipStream_t stream) {
  const float* X    = (const float*)d_in[0];
  const float* mask = (const float*)d_in[1];
  const float* Wq   = (const float*)d_in[2];
  const float* bq   = (const float*)d_in[3];
  const float* Wk   = (const float*)d_in[4];
  const float* bk   = (const float*)d_in[5];
  const float* Wv   = (const float*)d_in[6];
  const float* bv   = (const float*)d_in[7];
  const float* Wo   = (const float*)d_in[8];
  const float* bo   = (const float*)d_in[9];
  float* out   = (float*)d_out;
  float* state = out + (size_t)16384 * 1024;

  char* w = (char*)d_ws;
  unsigned short* Xb  = (unsigned short*)w; w += (size_t)16384 * 1024 * 2;
  unsigned short* Wkb = (unsigned short*)w; w += (size_t)1024 * 1024 * 2;
  unsigned short* Wvb = (unsigned short*)w; w += (size_t)1024 * 1024 * 2;
  unsigned short* SWb = (unsigned short*)w; w += (size_t)32 * 1024 * 2;
  float* WosT  = (float*)w; w += (size_t)16 * 1024 * 4;
  float* scal  = (float*)w; w += 256;
  float* dots2 = (float*)w; w += (size_t)32 * 16384 * 4;
  float* qsumT = (float*)w; w += (size_t)16 * 16384 * 4;
  float* dotbT = (float*)w; w += (size_t)16 * 16384 * 4;
  float* coef  = (float*)w; w += (size_t)16384 * 16 * 4;

  (void)hipFuncSetAttribute((const void*)k_dualgemm,
                            hipFuncAttributeMaxDynamicSharedMemorySize, 49152);

  hipLaunchKernelGGL(k_prep,     dim3(10433), dim3(256), 0, stream,
                     X, Xb, Wq, bq, Wk, bk, Wv, bv, Wo, Wkb, Wvb, SWb, WosT, scal);
  hipLaunchKernelGGL(k_dualgemm, dim3(1088), dim3(512), 49152, stream, Xb, Wkb, Wvb, SWb,
                     dots2, qsumT, dotbT);
  hipLaunchKernelGGL(k_cumsum,   dim3(64),   dim3(256), 0, stream, dots2, dotbT, qsumT, scal,
                     mask, coef, state);
  hipLaunchKernelGGL(k_outgemm,  dim3(512),  dim3(256), 0, stream, coef, WosT, bo, out);
}

// Round 7
// 118.321 us; speedup vs baseline: 1.0708x; 1.0708x over previous
//
#include <hip/hip_runtime.h>
#include <hip/hip_bf16.h>

// LinearAttention collapsed:
//   dots[m,h] = sum_{d in head h} (X@Wk^T)*(X@Wv^T)   [dual GEMM, A staged f32->bf16 in-kernel]
//   qsum = X @ Wqs^T ; dotb = X @ CB^T                 [piggybacked on bx==0 blocks]
//   cum = cumsum_s((dots + dotb + dbc)*mask^2); coef = cum*(qsum+bqs)
//   out = coef @ WosT + bo ; state[b,h,:,:] = cum[b, S-1, h]

typedef __attribute__((ext_vector_type(4))) float f32x4;
typedef __attribute__((ext_vector_type(8))) short bf16x8;
typedef __attribute__((ext_vector_type(8))) unsigned short u16x8;
typedef unsigned int u32;

#define GLDS16(g, l)                                                            \
  __builtin_amdgcn_global_load_lds((const __attribute__((address_space(1))) u32*)(g), \
                                   (__attribute__((address_space(3))) u32*)(l), 16, 0, 0)
#define MFMA16(a, b, c) __builtin_amdgcn_mfma_f32_16x16x32_bf16(a, b, c, 0, 0, 0)
#define LGK0 do { asm volatile("s_waitcnt lgkmcnt(0)" ::: "memory"); \
                  __builtin_amdgcn_sched_barrier(0); } while (0)

__device__ __forceinline__ unsigned short f2bf(float f) {
  union { float f; u32 u; } x; x.f = f;
  u32 r = (x.u + 0x7fffu + ((x.u >> 16) & 1u)) >> 16;
  return (unsigned short)r;
}

__device__ __forceinline__ bf16x8 pack8(const f32x4& lo, const f32x4& hi) {
  union { bf16x8 v; u32 w[4]; } r;
  union { __hip_bfloat162 h; u32 u; } c;
  c.h = __float22bfloat162_rn(make_float2(lo.x, lo.y)); r.w[0] = c.u;
  c.h = __float22bfloat162_rn(make_float2(lo.z, lo.w)); r.w[1] = c.u;
  c.h = __float22bfloat162_rn(make_float2(hi.x, hi.y)); r.w[2] = c.u;
  c.h = __float22bfloat162_rn(make_float2(hi.z, hi.w)); r.w[3] = c.u;
  return r.v;
}

// ---------------- prep: Wk/Wv->bf16 + weight sums (NO X convert anymore) ----------------
__global__ void k_prep(const float* __restrict__ Wq, const float* __restrict__ bq,
                       const float* __restrict__ Wk, const float* __restrict__ bk,
                       const float* __restrict__ Wv, const float* __restrict__ bv,
                       const float* __restrict__ Wo,
                       unsigned short* __restrict__ Wkb, unsigned short* __restrict__ Wvb,
                       unsigned short* __restrict__ SWb, float* __restrict__ WosT,
                       float* __restrict__ scal) {
  int blk = blockIdx.x, t = threadIdx.x;
  if (blk < 2048) {                    // Wk/Wv convert
    const float* src = (blk < 1024) ? Wk : Wv;
    unsigned short* dst = (blk < 1024) ? Wkb : Wvb;
    size_t i = ((size_t)(blk & 1023) * 256 + t) * 4;
    f32x4 v = *(const f32x4*)(src + i);
    dst[i + 0] = f2bf(v.x); dst[i + 1] = f2bf(v.y);
    dst[i + 2] = f2bf(v.z); dst[i + 3] = f2bf(v.w);
  } else {                             // weight sums
    int b2 = blk - 2048;
    if (b2 < 128) {
      int o = b2 * 256 + t;
      int r = o >> 10, c = o & 1023;
      float s = 0.f;
      if (r < 16) {
        for (int d = 0; d < 64; ++d) s += Wq[(size_t)(r * 64 + d) * 1024 + c];
      } else {
        int h = r - 16;
        for (int d = 0; d < 64; ++d) {
          int j = h * 64 + d;
          s += bv[j] * Wk[(size_t)j * 1024 + c] + bk[j] * Wv[(size_t)j * 1024 + c];
        }
      }
      SWb[o] = f2bf(s);
    } else if (b2 < 192) {
      int o = (b2 - 128) * 256 + t;
      int h = o >> 10, j = o & 1023;
      float s = 0.f;
      for (int d = 0; d < 64; ++d) s += Wo[(size_t)j * 1024 + h * 64 + d];
      WosT[o] = s;
    } else {
      if (t < 16) {
        float s = 0.f;
        for (int d = 0; d < 64; ++d) s += bq[t * 64 + d];
        scal[t] = s;
      } else if (t < 32) {
        int h = t - 16;
        float s = 0.f;
        for (int d = 0; d < 64; ++d) s += bk[h * 64 + d] * bv[h * 64 + d];
        scal[t] = s;
      }
    }
  }
}

// ---------------- dual GEMM: BM=256, BN=128, BK=32, 8 waves (4M x 2N) ----------------
// A staged DIRECTLY from X (f32) via global_load_lds; converted to bf16 at frag read.
// 3 buffers, depth-2 prefetch, counted vmcnt(6), ONE barrier per tile, 2x16-MFMA halves.
// LDS (bytes): A f32 3x32768 @0; B bf16 3x16384 @98304 (Bk+Bv); SW 3x2048 @147456. =153600.
// A f32 row = 128 B = 8 units: unit ^= (row&7). B/SW bf16 row = 64 B: unit ^= (row>>1)&3.
#define NT 32
__global__ __launch_bounds__(512, 2) void k_dualgemm(
    const float* __restrict__ X,
    const unsigned short* __restrict__ Wkb,
    const unsigned short* __restrict__ Wvb,
    const unsigned short* __restrict__ SWb,
    float* __restrict__ dotsT, float* __restrict__ qsumT, float* __restrict__ dotbT) {
  extern __shared__ __align__(16) char ldsb[];
  float* Af = (float*)ldsb;                                  // 3 x 8192 f32
  unsigned short* Bb = (unsigned short*)(ldsb + 98304);      // 3 x 8192 us (Bk 4096 + Bv 4096)
  unsigned short* Sw = (unsigned short*)(ldsb + 147456);     // 3 x 1024 us
  int orig = blockIdx.x;
  int wg = (orig & 7) * 64 + (orig >> 3);    // XCD-chunked swizzle (512 % 8 == 0)
  int bx = wg & 7, by = wg >> 3;
  int row0 = by << 8, col0 = bx << 7;
  int tid = threadIdx.x, wid = tid >> 6, lane = tid & 63;
  int wrM = wid >> 1, wcN = wid & 1;
  int fr = lane & 15, fg = lane >> 4;
  bool side = (bx == 0);
  bool stageSW = side && (wid < 2);

  // ---- staging sources ----
  const float* sA[4];
#pragma unroll
  for (int c = 0; c < 4; ++c) {
    int U = c * 512 + tid, r = U >> 3, g = (U & 7) ^ (r & 7);
    sA[c] = X + (size_t)(row0 + r) * 1024 + g * 4;
  }
  const unsigned short *sK, *sV, *sS;
  {
    int r = tid >> 2, s = tid & 3, g = s ^ ((r >> 1) & 3);
    sK = Wkb + (size_t)(col0 + r) * 1024 + g * 8;
    sV = Wvb + (size_t)(col0 + r) * 1024 + g * 8;
    int rs = (tid & 127) >> 2, ss = tid & 3, gs = ss ^ ((rs >> 1) & 3);
    sS = SWb + (size_t)rs * 1024 + gs * 8;
  }
  // wave-uniform LDS dest components
  int dA = tid << 2;            // f32 elems: U*4 per chunk-c adds c*2048
  int dB = tid << 3;            // us elems (Bk); Bv at +4096
  int dS = tid << 3;            // tid < 128

  // ---- fragment read offsets ----
  int keyA = fr & 7, s0 = (2 * fg) ^ keyA;
  int aoffL[4], aoffH[4];       // f32 elems within A buf
#pragma unroll
  for (int mi = 0; mi < 4; ++mi) {
    int R = wrM * 64 + mi * 16 + fr;
    aoffL[mi] = R * 32 + s0 * 4;
    aoffH[mi] = R * 32 + (s0 ^ 1) * 4;
  }
  int ubo = (fg ^ ((fr >> 1) & 3)) << 3;
  int bko[4], bvo[4];
#pragma unroll
  for (int ni = 0; ni < 4; ++ni) {
    bko[ni] = (wcN * 64 + ni * 16 + fr) * 32 + ubo;
    bvo[ni] = 4096 + (wcN * 64 + ni * 16 + fr) * 32 + ubo;
  }
  int swo = (wcN * 16 + fr) * 32 + ubo;

  f32x4 ck[4][4] = {{0}}, cv[4][4] = {{0}};
  f32x4 qa[4] = {0, 0, 0, 0};

  // ---- prologue: stage tiles 0,1 ----
#pragma unroll
  for (int p = 0; p < 2; ++p) {
    int ko = p << 5;
#pragma unroll
    for (int c = 0; c < 4; ++c) GLDS16(sA[c] + ko, Af + p * 8192 + c * 2048 + dA);
    GLDS16(sK + ko, Bb + p * 8192 + dB);
    GLDS16(sV + ko, Bb + p * 8192 + 4096 + dB);
    if (stageSW) GLDS16(sS + ko, Sw + p * 1024 + dS);
  }
  asm volatile("s_waitcnt vmcnt(6)" ::: "memory");
  __builtin_amdgcn_s_barrier();

  int bufR = 0;
  for (int t = 0; t < NT; ++t) {
    const float* ArB = Af + bufR * 8192;
    const unsigned short* BkB = Bb + bufR * 8192;
    const unsigned short* SwB = Sw + bufR * 1024;
    const int bufW = (bufR + 2 >= 3) ? bufR - 1 : bufR + 2;
    const int ko = (t + 2) << 5;
    const bool st = (t + 2 < NT);

    // ---- half 1: A frags (f32, 8 ds_read) + Bk -> ck (16 MFMA)
    f32x4 alo[4], ahi[4];
#pragma unroll
    for (int mi = 0; mi < 4; ++mi) {
      alo[mi] = *(const f32x4*)(ArB + aoffL[mi]);
      ahi[mi] = *(const f32x4*)(ArB + aoffH[mi]);
    }
    if (st) {
#pragma unroll
      for (int c = 0; c < 4; ++c) GLDS16(sA[c] + ko, Af + bufW * 8192 + c * 2048 + dA);
    }
    bf16x8 bk[4];
#pragma unroll
    for (int ni = 0; ni < 4; ++ni) bk[ni] = *(const bf16x8*)(BkB + bko[ni]);
    LGK0;
    bf16x8 a[4];
#pragma unroll
    for (int mi = 0; mi < 4; ++mi) a[mi] = pack8(alo[mi], ahi[mi]);
    __builtin_amdgcn_s_setprio(1);
#pragma unroll
    for (int mi = 0; mi < 4; ++mi)
#pragma unroll
      for (int ni = 0; ni < 4; ++ni)
        ck[mi][ni] = MFMA16(a[mi], bk[ni], ck[mi][ni]);
    __builtin_amdgcn_s_setprio(0);

    // ---- half 2: Bv (+SW) -> cv (16 MFMA) (+4 side)
    bf16x8 bv[4], sw;
#pragma unroll
    for (int ni = 0; ni < 4; ++ni) bv[ni] = *(const bf16x8*)(BkB + bvo[ni]);
    if (side) sw = *(const bf16x8*)(SwB + swo);
    if (st) {
      GLDS16(sK + ko, Bb + bufW * 8192 + dB);
      GLDS16(sV + ko, Bb + bufW * 8192 + 4096 + dB);
      if (stageSW) GLDS16(sS + ko, Sw + bufW * 1024 + dS);
    }
    LGK0;
    __builtin_amdgcn_s_setprio(1);
#pragma unroll
    for (int mi = 0; mi < 4; ++mi)
#pragma unroll
      for (int ni = 0; ni < 4; ++ni)
        cv[mi][ni] = MFMA16(a[mi], bv[ni], cv[mi][ni]);
    if (side) {
#pragma unroll
      for (int mi = 0; mi < 4; ++mi) qa[mi] = MFMA16(a[mi], sw, qa[mi]);
    }
    __builtin_amdgcn_s_setprio(0);

    // tile boundary: counted vmcnt (t+1's 6 loads must be done; t+2's may fly)
    if (t <= NT - 3) { asm volatile("s_waitcnt vmcnt(6)" ::: "memory"); }
    else             { asm volatile("s_waitcnt vmcnt(0)" ::: "memory"); }
    __builtin_amdgcn_s_barrier();
    bufR = (bufR + 1 >= 3) ? 0 : bufR + 1;
  }

  // ---- epilogue: dots = per-head sum over 64 cols of ck*cv ----
  float part[4][4];
#pragma unroll
  for (int mi = 0; mi < 4; ++mi)
#pragma unroll
    for (int q = 0; q < 4; ++q) {
      float s = 0.f;
#pragma unroll
      for (int ni = 0; ni < 4; ++ni) s += ck[mi][ni][q] * cv[mi][ni][q];
      part[mi][q] = s;
    }
#pragma unroll
  for (int r = 0; r < 4; ++r) {
#pragma unroll
    for (int mi = 0; mi < 4; ++mi)
#pragma unroll
      for (int q = 0; q < 4; ++q)
        part[mi][q] += __shfl_xor(part[mi][q], 1 << r, 64);
  }
  int h = bx * 2 + wcN;
  if (fr == 0) {
#pragma unroll
    for (int mi = 0; mi < 4; ++mi)
#pragma unroll
      for (int q = 0; q < 4; ++q)
        dotsT[(size_t)h * 16384 + row0 + wrM * 64 + mi * 16 + fg * 4 + q] = part[mi][q];
  }
  if (side) {
    float* dst = (wcN == 0) ? qsumT : dotbT;
#pragma unroll
    for (int mi = 0; mi < 4; ++mi)
#pragma unroll
      for (int q = 0; q < 4; ++q)
        dst[(size_t)fr * 16384 + row0 + wrM * 64 + mi * 16 + fg * 4 + q] = qa[mi][q];
  }
}

// ---------------- cumsum + coef + state ----------------
__global__ void k_cumsum(const float* __restrict__ dotsT, const float* __restrict__ dotbT,
                         const float* __restrict__ qsumT, const float* __restrict__ scal,
                         const float* __restrict__ mask,
                         float* __restrict__ coef, float* __restrict__ state) {
  __shared__ float csum[256];
  int b = blockIdx.x >> 4, h = blockIdx.x & 15;
  int t = threadIdx.x;
  float bqs = scal[h], dbc = scal[16 + h];
  size_t m0 = (size_t)b * 4096;
  const float* dro = dotsT + (size_t)h * 16384 + m0;
  const float* dbo = dotbT + (size_t)h * 16384 + m0;
  const float* qso = qsumT + (size_t)h * 16384 + m0;
  const float* mko = mask + m0;
  float loc[16], run = 0.f;
  int s0 = t * 16;
#pragma unroll
  for (int i = 0; i < 16; ++i) {
    int ii = s0 + i;
    float mk = mko[ii];
    float d = (dro[ii] + dbo[ii] + dbc) * mk * mk;
    run += d;
    loc[i] = run;
  }
  csum[t] = run;
  __syncthreads();
  for (int off = 1; off < 256; off <<= 1) {
    float v = (t >= off) ? csum[t - off] : 0.f;
    __syncthreads();
    csum[t] += v;
    __syncthreads();
  }
  float prefix = csum[t] - run;
#pragma unroll
  for (int i = 0; i < 16; ++i) {
    int ii = s0 + i;
    float cum = prefix + loc[i];
    coef[(m0 + ii) * 16 + h] = cum * (qso[ii] + bqs);
  }
  float total = csum[255];
  float* sp = state + (size_t)(b * 16 + h) * 4096;
  for (int i = t; i < 4096; i += 256) sp[i] = total;
}

// ---------------- output GEMM: out = coef(16384x16) @ WosT(16x1024) + bo ----------------
__global__ __launch_bounds__(256) void k_outgemm(const float* __restrict__ coef,
                                                 const float* __restrict__ WosT,
                                                 const float* __restrict__ bo,
                                                 float* __restrict__ out) {
  int t = threadIdx.x;
  int j0 = t * 4;
  f32x4 w4[16];
#pragma unroll
  for (int hh = 0; hh < 16; ++hh) w4[hh] = *(const f32x4*)&WosT[hh * 1024 + j0];
  f32x4 bov = *(const f32x4*)&bo[j0];
  size_t m0 = (size_t)blockIdx.x * 32;
  for (int mi = 0; mi < 32; ++mi) {
    size_t m = m0 + mi;
    const float* cm = &coef[m * 16];
    f32x4 acc = bov;
#pragma unroll
    for (int hh = 0; hh < 16; ++hh) acc += w4[hh] * cm[hh];
    *(f32x4*)&out[m * 1024 + j0] = acc;
  }
}

extern "C" void kernel_launch(void* const* d_in, const int* in_sizes, int n_in,
                              void* d_out, int out_size, void* d_ws, size_t ws_size,
                              hipStream_t stream) {
  const float* X    = (const float*)d_in[0];
  const float* mask = (const float*)d_in[1];
  const float* Wq   = (const float*)d_in[2];
  const float* bq   = (const float*)d_in[3];
  const float* Wk   = (const float*)d_in[4];
  const float* bk   = (const float*)d_in[5];
  const float* Wv   = (const float*)d_in[6];
  const float* bv   = (const float*)d_in[7];
  const float* Wo   = (const float*)d_in[8];
  const float* bo   = (const float*)d_in[9];
  float* out   = (float*)d_out;
  float* state = out + (size_t)16384 * 1024;

  char* w = (char*)d_ws;
  unsigned short* Wkb = (unsigned short*)w; w += (size_t)1024 * 1024 * 2;
  unsigned short* Wvb = (unsigned short*)w; w += (size_t)1024 * 1024 * 2;
  unsigned short* SWb = (unsigned short*)w; w += (size_t)32 * 1024 * 2;
  float* WosT  = (float*)w; w += (size_t)16 * 1024 * 4;
  float* scal  = (float*)w; w += 256;
  float* dotsT = (float*)w; w += (size_t)16 * 16384 * 4;
  float* qsumT = (float*)w; w += (size_t)16 * 16384 * 4;
  float* dotbT = (float*)w; w += (size_t)16 * 16384 * 4;
  float* coef  = (float*)w; w += (size_t)16384 * 16 * 4;

  (void)hipFuncSetAttribute((const void*)k_dualgemm,
                            hipFuncAttributeMaxDynamicSharedMemorySize, 153600);

  hipLaunchKernelGGL(k_prep,     dim3(2241), dim3(256), 0, stream,
                     Wq, bq, Wk, bk, Wv, bv, Wo, Wkb, Wvb, SWb, WosT, scal);
  hipLaunchKernelGGL(k_dualgemm, dim3(512),  dim3(512), 153600, stream, X, Wkb, Wvb, SWb,
                     dotsT, qsumT, dotbT);
  hipLaunchKernelGGL(k_cumsum,   dim3(64),   dim3(256), 0, stream, dotsT, dotbT, qsumT, scal,
                     mask, coef, state);
  hipLaunchKernelGGL(k_outgemm,  dim3(512),  dim3(256), 0, stream, coef, WosT, bo, out);
}

// Round 8
// 110.269 us; speedup vs baseline: 1.1490x; 1.0730x over previous
//
#include <hip/hip_runtime.h>
#include <hip/hip_bf16.h>

// LinearAttention collapsed:
//   dots[m,h] = sum_{d in head h} (X@Wk^T)*(X@Wv^T)   [dual GEMM, A reg-staged f32->bf16]
//   qsum = X @ Wqs^T ; dotb = X @ CB^T                 [piggybacked on bx==0 blocks]
//   cum = cumsum_s((dots + dotb + dbc)*mask^2); coef = cum*(qsum+bqs)
//   out = coef @ WosT + bo ; state[b,h,:,:] = cum[b, S-1, h]

typedef __attribute__((ext_vector_type(4))) float f32x4;
typedef __attribute__((ext_vector_type(8))) short bf16x8;
typedef __attribute__((ext_vector_type(8))) unsigned short u16x8;
typedef unsigned int u32;

#define GLDS16(g, l)                                                            \
  __builtin_amdgcn_global_load_lds((const __attribute__((address_space(1))) u32*)(g), \
                                   (__attribute__((address_space(3))) u32*)(l), 16, 0, 0)
#define MFMA16(a, b, c) __builtin_amdgcn_mfma_f32_16x16x32_bf16(a, b, c, 0, 0, 0)
#define LGK0 do { asm volatile("s_waitcnt lgkmcnt(0)" ::: "memory"); \
                  __builtin_amdgcn_sched_barrier(0); } while (0)

__device__ __forceinline__ unsigned short f2bf(float f) {
  union { float f; u32 u; } x; x.f = f;
  u32 r = (x.u + 0x7fffu + ((x.u >> 16) & 1u)) >> 16;
  return (unsigned short)r;
}

__device__ __forceinline__ bf16x8 pack8(const f32x4& lo, const f32x4& hi) {
  union { bf16x8 v; u32 w[4]; } r;
  union { __hip_bfloat162 h; u32 u; } c;
  c.h = __float22bfloat162_rn(make_float2(lo.x, lo.y)); r.w[0] = c.u;
  c.h = __float22bfloat162_rn(make_float2(lo.z, lo.w)); r.w[1] = c.u;
  c.h = __float22bfloat162_rn(make_float2(hi.x, hi.y)); r.w[2] = c.u;
  c.h = __float22bfloat162_rn(make_float2(hi.z, hi.w)); r.w[3] = c.u;
  return r.v;
}

// ---------------- prep: Wk/Wv->bf16 + weight sums (no X convert) ----------------
__global__ void k_prep(const float* __restrict__ Wq, const float* __restrict__ bq,
                       const float* __restrict__ Wk, const float* __restrict__ bk,
                       const float* __restrict__ Wv, const float* __restrict__ bv,
                       const float* __restrict__ Wo,
                       unsigned short* __restrict__ Wkb, unsigned short* __restrict__ Wvb,
                       unsigned short* __restrict__ SWb, float* __restrict__ WosT,
                       float* __restrict__ scal) {
  int blk = blockIdx.x, t = threadIdx.x;
  if (blk < 2048) {
    const float* src = (blk < 1024) ? Wk : Wv;
    unsigned short* dst = (blk < 1024) ? Wkb : Wvb;
    size_t i = ((size_t)(blk & 1023) * 256 + t) * 4;
    f32x4 v = *(const f32x4*)(src + i);
    dst[i + 0] = f2bf(v.x); dst[i + 1] = f2bf(v.y);
    dst[i + 2] = f2bf(v.z); dst[i + 3] = f2bf(v.w);
  } else {
    int b2 = blk - 2048;
    if (b2 < 128) {
      int o = b2 * 256 + t;
      int r = o >> 10, c = o & 1023;
      float s = 0.f;
      if (r < 16) {
        for (int d = 0; d < 64; ++d) s += Wq[(size_t)(r * 64 + d) * 1024 + c];
      } else {
        int h = r - 16;
        for (int d = 0; d < 64; ++d) {
          int j = h * 64 + d;
          s += bv[j] * Wk[(size_t)j * 1024 + c] + bk[j] * Wv[(size_t)j * 1024 + c];
        }
      }
      SWb[o] = f2bf(s);
    } else if (b2 < 192) {
      int o = (b2 - 128) * 256 + t;
      int h = o >> 10, j = o & 1023;
      float s = 0.f;
      for (int d = 0; d < 64; ++d) s += Wo[(size_t)j * 1024 + h * 64 + d];
      WosT[o] = s;
    } else {
      if (t < 16) {
        float s = 0.f;
        for (int d = 0; d < 64; ++d) s += bq[t * 64 + d];
        scal[t] = s;
      } else if (t < 32) {
        int h = t - 16;
        float s = 0.f;
        for (int d = 0; d < 64; ++d) s += bk[h * 64 + d] * bv[h * 64 + d];
        scal[t] = s;
      }
    }
  }
}

// ---------------- dual GEMM: BM=256, BN=128, BK=32, 8 waves (4M x 2N) ----------------
// R2 body (bf16 LDS, 4 bufs, 2x16-MFMA halves, 1 barrier/tile) + A reg-staged from X f32:
// issue 4x global_load_dwordx4 in half-1, convert+ds_write at tile boundary (after vmcnt).
// B (Wk/Wv/SW) staged depth-3 via global_load_lds. Per-wave vmem queue per tile:
// [KV(t+2)][A(t+1)x4][KV(t+3)] -> boundary vmcnt(2) (SW-waves 3) drains A(t+1).
// Buffer (elems): A@0 (8192), Bk@8192 (4096), Bv@12288 (4096), SW@16384 (1024) = 17408.
// 4 buffers = 139264 B. bf16 rows 64B = 4 units; swizzle key (row>>1)&3 (0-conflict, R2).
#define NT 32
#define BUFS 17408
__global__ __launch_bounds__(512, 2) void k_dualgemm(
    const float* __restrict__ X,
    const unsigned short* __restrict__ Wkb,
    const unsigned short* __restrict__ Wvb,
    const unsigned short* __restrict__ SWb,
    float* __restrict__ dotsT, float* __restrict__ qsumT, float* __restrict__ dotbT) {
  extern __shared__ __align__(16) unsigned short lds[];
  int orig = blockIdx.x;
  int wg = (orig & 7) * 64 + (orig >> 3);    // XCD-chunked swizzle (512 % 8 == 0)
  int bx = wg & 7, by = wg >> 3;
  int row0 = by << 8, col0 = bx << 7;
  int tid = threadIdx.x, wid = tid >> 6, lane = tid & 63;
  int wrM = wid >> 1, wcN = wid & 1;
  int fr = lane & 15, fg = lane >> 4;
  bool side = (bx == 0);
  bool swv = side && (wid < 2);

  // ---- A reg-stage addressing: thread owns 16B-units U=tid (rows 0-127) and tid+512 ----
  int rA = tid >> 2, sA = tid & 3;
  int gA = sA ^ ((tid >> 3) & 3);            // logical unit (swizzle key (r>>1)&3)
  const float* pA0 = X + (size_t)(row0 + rA) * 1024 + gA * 8;
  const float* pA1 = pA0 + (size_t)128 * 1024;
  int wo0 = rA * 32 + sA * 8;                // stored LDS elem offset (row-major + slot)
  int wo1 = wo0 + 4096;

  // ---- B/SW staging sources (pre-swizzled 16B units) ----
  int rB = tid >> 2;
  int uswB = (((tid & 3) ^ ((tid >> 3) & 3)) << 3);
  const unsigned short* sK = Wkb + (size_t)(col0 + rB) * 1024 + uswB;
  const unsigned short* sV = Wvb + (size_t)(col0 + rB) * 1024 + uswB;
  const unsigned short* sS = SWb + (size_t)(tid >> 2) * 1024 + uswB;   // tid<128 only
  int dK = 8192 + (wid << 9), dV = 12288 + (wid << 9), dS = 16384 + (wid << 9);

  // ---- fragment read offsets (R2-proven) ----
  int ubo = (fg ^ ((fr >> 1) & 3)) << 3;
  int aro = (wrM * 64 + fr) * 32 + ubo;            // + mi*512
  int bro = (wcN * 64 + fr) * 32 + ubo;            // + ni*512
  int swo = 16384 + (wcN * 16 + fr) * 32 + ubo;

  f32x4 ck[4][4] = {{0}}, cv[4][4] = {{0}};
  f32x4 qa[4] = {0, 0, 0, 0};

  // ---- prologue: A(0) to regs; B tiles 0,1,2 via glds; write A(0) ----
  {
    f32x4 xl0 = *(const f32x4*)(pA0);     f32x4 xh0 = *(const f32x4*)(pA0 + 4);
    f32x4 xl1 = *(const f32x4*)(pA1);     f32x4 xh1 = *(const f32x4*)(pA1 + 4);
#pragma unroll
    for (int p = 0; p < 3; ++p) {
      int ko = p << 5;
      GLDS16(sK + ko, lds + p * BUFS + dK);
      GLDS16(sV + ko, lds + p * BUFS + dV);
      if (swv) GLDS16(sS + ko, lds + p * BUFS + dS);
    }
    if (swv) { asm volatile("s_waitcnt vmcnt(6)" ::: "memory"); }
    else     { asm volatile("s_waitcnt vmcnt(4)" ::: "memory"); }
    *(bf16x8*)(lds + wo0) = pack8(xl0, xh0);
    *(bf16x8*)(lds + wo1) = pack8(xl1, xh1);
    asm volatile("s_waitcnt lgkmcnt(0)" ::: "memory");
    __builtin_amdgcn_s_barrier();
  }

  for (int t = 0; t < NT; ++t) {
    const int rb = (t & 3) * BUFS;
    const bool st1 = (t + 1 < NT);
    const bool st3 = (t + 3 < NT);
    const int ko1 = (t + 1) << 5;
    const int ko3 = (t + 3) << 5;
    const int wb3 = ((t + 3) & 3) * BUFS;

    // ---- half 1: A frags + Bk -> ck (16 MFMA); issue A(t+1) global loads
    bf16x8 a[4], bk[4];
#pragma unroll
    for (int mi = 0; mi < 4; ++mi) a[mi] = *(const bf16x8*)(lds + rb + aro + mi * 512);
#pragma unroll
    for (int ni = 0; ni < 4; ++ni) bk[ni] = *(const bf16x8*)(lds + rb + 8192 + bro + ni * 512);
    f32x4 xl0, xh0, xl1, xh1;
    if (st1) {
      xl0 = *(const f32x4*)(pA0 + ko1); xh0 = *(const f32x4*)(pA0 + ko1 + 4);
      xl1 = *(const f32x4*)(pA1 + ko1); xh1 = *(const f32x4*)(pA1 + ko1 + 4);
    }
    LGK0;
    __builtin_amdgcn_s_setprio(1);
#pragma unroll
    for (int mi = 0; mi < 4; ++mi)
#pragma unroll
      for (int ni = 0; ni < 4; ++ni)
        ck[mi][ni] = MFMA16(a[mi], bk[ni], ck[mi][ni]);
    __builtin_amdgcn_s_setprio(0);

    // ---- half 2: Bv (+SW) -> cv (16 MFMA) (+4 side); issue B(t+3) glds
    bf16x8 bv[4], sw;
#pragma unroll
    for (int ni = 0; ni < 4; ++ni) bv[ni] = *(const bf16x8*)(lds + rb + 12288 + bro + ni * 512);
    if (side) sw = *(const bf16x8*)(lds + rb + swo);
    if (st3) {
      GLDS16(sK + ko3, lds + wb3 + dK);
      GLDS16(sV + ko3, lds + wb3 + dV);
      if (swv) GLDS16(sS + ko3, lds + wb3 + dS);
    }
    LGK0;
    __builtin_amdgcn_s_setprio(1);
#pragma unroll
    for (int mi = 0; mi < 4; ++mi)
#pragma unroll
      for (int ni = 0; ni < 4; ++ni)
        cv[mi][ni] = MFMA16(a[mi], bv[ni], cv[mi][ni]);
    if (side) {
#pragma unroll
      for (int mi = 0; mi < 4; ++mi) qa[mi] = MFMA16(a[mi], sw, qa[mi]);
    }
    __builtin_amdgcn_s_setprio(0);

    // ---- boundary: drain A(t+1), convert+write, retire writes, barrier
    if (st1) {
      if (t < NT - 3) {
        if (swv) { asm volatile("s_waitcnt vmcnt(3)" ::: "memory"); }
        else     { asm volatile("s_waitcnt vmcnt(2)" ::: "memory"); }
      } else {
        asm volatile("s_waitcnt vmcnt(0)" ::: "memory");
      }
      unsigned short* Aw = lds + ((t + 1) & 3) * BUFS;
      *(bf16x8*)(Aw + wo0) = pack8(xl0, xh0);
      *(bf16x8*)(Aw + wo1) = pack8(xl1, xh1);
      asm volatile("s_waitcnt lgkmcnt(0)" ::: "memory");
    } else {
      asm volatile("s_waitcnt vmcnt(0)" ::: "memory");
    }
    __builtin_amdgcn_s_barrier();
  }

  // ---- epilogue: dots = per-head sum over 64 cols of ck*cv ----
  float part[4][4];
#pragma unroll
  for (int mi = 0; mi < 4; ++mi)
#pragma unroll
    for (int q = 0; q < 4; ++q) {
      float s = 0.f;
#pragma unroll
      for (int ni = 0; ni < 4; ++ni) s += ck[mi][ni][q] * cv[mi][ni][q];
      part[mi][q] = s;
    }
#pragma unroll
  for (int r = 0; r < 4; ++r) {
#pragma unroll
    for (int mi = 0; mi < 4; ++mi)
#pragma unroll
      for (int q = 0; q < 4; ++q)
        part[mi][q] += __shfl_xor(part[mi][q], 1 << r, 64);
  }
  int h = bx * 2 + wcN;
  if (fr == 0) {
#pragma unroll
    for (int mi = 0; mi < 4; ++mi)
#pragma unroll
      for (int q = 0; q < 4; ++q)
        dotsT[(size_t)h * 16384 + row0 + wrM * 64 + mi * 16 + fg * 4 + q] = part[mi][q];
  }
  if (side) {
    float* dst = (wcN == 0) ? qsumT : dotbT;
#pragma unroll
    for (int mi = 0; mi < 4; ++mi)
#pragma unroll
      for (int q = 0; q < 4; ++q)
        dst[(size_t)fr * 16384 + row0 + wrM * 64 + mi * 16 + fg * 4 + q] = qa[mi][q];
  }
}

// ---------------- cumsum + coef + state ----------------
__global__ void k_cumsum(const float* __restrict__ dotsT, const float* __restrict__ dotbT,
                         const float* __restrict__ qsumT, const float* __restrict__ scal,
                         const float* __restrict__ mask,
                         float* __restrict__ coef, float* __restrict__ state) {
  __shared__ float csum[256];
  int b = blockIdx.x >> 4, h = blockIdx.x & 15;
  int t = threadIdx.x;
  float bqs = scal[h], dbc = scal[16 + h];
  size_t m0 = (size_t)b * 4096;
  const float* dro = dotsT + (size_t)h * 16384 + m0;
  const float* dbo = dotbT + (size_t)h * 16384 + m0;
  const float* qso = qsumT + (size_t)h * 16384 + m0;
  const float* mko = mask + m0;
  float loc[16], run = 0.f;
  int s0 = t * 16;
#pragma unroll
  for (int i = 0; i < 16; ++i) {
    int ii = s0 + i;
    float mk = mko[ii];
    float d = (dro[ii] + dbo[ii] + dbc) * mk * mk;
    run += d;
    loc[i] = run;
  }
  csum[t] = run;
  __syncthreads();
  for (int off = 1; off < 256; off <<= 1) {
    float v = (t >= off) ? csum[t - off] : 0.f;
    __syncthreads();
    csum[t] += v;
    __syncthreads();
  }
  float prefix = csum[t] - run;
#pragma unroll
  for (int i = 0; i < 16; ++i) {
    int ii = s0 + i;
    float cum = prefix + loc[i];
    coef[(m0 + ii) * 16 + h] = cum * (qso[ii] + bqs);
  }
  float total = csum[255];
  float* sp = state + (size_t)(b * 16 + h) * 4096;
  for (int i = t; i < 4096; i += 256) sp[i] = total;
}

// ---------------- output GEMM: out = coef(16384x16) @ WosT(16x1024) + bo ----------------
__global__ __launch_bounds__(256) void k_outgemm(const float* __restrict__ coef,
                                                 const float* __restrict__ WosT,
                                                 const float* __restrict__ bo,
                                                 float* __restrict__ out) {
  int t = threadIdx.x;
  int j0 = t * 4;
  f32x4 w4[16];
#pragma unroll
  for (int hh = 0; hh < 16; ++hh) w4[hh] = *(const f32x4*)&WosT[hh * 1024 + j0];
  f32x4 bov = *(const f32x4*)&bo[j0];
  size_t m0 = (size_t)blockIdx.x * 32;
  for (int mi = 0; mi < 32; ++mi) {
    size_t m = m0 + mi;
    const float* cm = &coef[m * 16];
    f32x4 acc = bov;
#pragma unroll
    for (int hh = 0; hh < 16; ++hh) acc += w4[hh] * cm[hh];
    *(f32x4*)&out[m * 1024 + j0] = acc;
  }
}

extern "C" void kernel_launch(void* const* d_in, const int* in_sizes, int n_in,
                              void* d_out, int out_size, void* d_ws, size_t ws_size,
                              hipStream_t stream) {
  const float* X    = (const float*)d_in[0];
  const float* mask = (const float*)d_in[1];
  const float* Wq   = (const float*)d_in[2];
  const float* bq   = (const float*)d_in[3];
  const float* Wk   = (const float*)d_in[4];
  const float* bk   = (const float*)d_in[5];
  const float* Wv   = (const float*)d_in[6];
  const float* bv   = (const float*)d_in[7];
  const float* Wo   = (const float*)d_in[8];
  const float* bo   = (const float*)d_in[9];
  float* out   = (float*)d_out;
  float* state = out + (size_t)16384 * 1024;

  char* w = (char*)d_ws;
  unsigned short* Wkb = (unsigned short*)w; w += (size_t)1024 * 1024 * 2;
  unsigned short* Wvb = (unsigned short*)w; w += (size_t)1024 * 1024 * 2;
  unsigned short* SWb = (unsigned short*)w; w += (size_t)32 * 1024 * 2;
  float* WosT  = (float*)w; w += (size_t)16 * 1024 * 4;
  float* scal  = (float*)w; w += 256;
  float* dotsT = (float*)w; w += (size_t)16 * 16384 * 4;
  float* qsumT = (float*)w; w += (size_t)16 * 16384 * 4;
  float* dotbT = (float*)w; w += (size_t)16 * 16384 * 4;
  float* coef  = (float*)w; w += (size_t)16384 * 16 * 4;

  (void)hipFuncSetAttribute((const void*)k_dualgemm,
                            hipFuncAttributeMaxDynamicSharedMemorySize, 139264);

  hipLaunchKernelGGL(k_prep,     dim3(2241), dim3(256), 0, stream,
                     Wq, bq, Wk, bk, Wv, bv, Wo, Wkb, Wvb, SWb, WosT, scal);
  hipLaunchKernelGGL(k_dualgemm, dim3(512),  dim3(512), 139264, stream, X, Wkb, Wvb, SWb,
                     dotsT, qsumT, dotbT);
  hipLaunchKernelGGL(k_cumsum,   dim3(64),   dim3(256), 0, stream, dotsT, dotbT, qsumT, scal,
                     mask, coef, state);
  hipLaunchKernelGGL(k_outgemm,  dim3(512),  dim3(256), 0, stream, coef, WosT, bo, out);
}